// Round 2
// baseline (3425.880 us; speedup 1.0000x reference)
//
#include <hip/hip_runtime.h>

// RGCN on MI355X. CSR-by-dst built once, then per conv:
//   Phase A: S[n, b*100+d] = sum_{e: dst=n} att[type_e,b]*norm_e*invdeg_n * x[src_e,d]
//   Phase B: out = [S | x] @ [basis_flat ; root] + bias   (virtual K=1100 fp32 GEMM,
//            K-split over 2 blocks with atomicAdd accumulation into zeroed out)
// Layer chain: L0(set1) -> L1(set1,relu) -> L2(set2) -> L3(set1,relu) -> L4(set3)

#define DIMD 100
#define NBASES 10
#define KTOT 1100          // 1000 (S@basis) + 100 (x@root)
#define KC 32              // k per chunk
#define NCHUNK 35          // 35*32 = 1120 >= 1100 (tail zero-padded)
#define SPLIT0 18          // chunks in split 0 (k 0..575); split 1: 17 chunks

static inline size_t align256(size_t x) { return (x + 255) & ~(size_t)255; }

// ---------------- preprocessing kernels ----------------

__global__ __launch_bounds__(256) void hist_kernel(const int* __restrict__ dst,
                                                   int* __restrict__ counts, int E) {
    int e = blockIdx.x * 256 + threadIdx.x;
    if (e < E) atomicAdd(&counts[dst[e]], 1);
}

__global__ __launch_bounds__(1024) void scan_kernel(const int* __restrict__ counts,
                                                    int* __restrict__ row_ptr,
                                                    int* __restrict__ next_pos, int n) {
    __shared__ int part[1024];
    __shared__ int base_s[1024];
    int t = threadIdx.x;
    int chunk = (n + 1023) / 1024;
    int lo = t * chunk, hi = min(lo + chunk, n);
    int s = 0;
    for (int i = lo; i < hi; ++i) s += counts[i];
    part[t] = s;
    __syncthreads();
    if (t == 0) {
        int run = 0;
        for (int i = 0; i < 1024; ++i) { int v = part[i]; base_s[i] = run; run += v; }
        row_ptr[n] = run;   // == E
    }
    __syncthreads();
    int run = base_s[t];
    for (int i = lo; i < hi; ++i) {
        row_ptr[i] = run;
        next_pos[i] = run;
        run += counts[i];
    }
}

__global__ __launch_bounds__(256) void scatter_kernel(
        const int* __restrict__ src, const int* __restrict__ dst,
        const int* __restrict__ etype, const float* __restrict__ enorm,
        const int* __restrict__ counts, int* __restrict__ next_pos,
        int* __restrict__ ssrc, int* __restrict__ stype, float* __restrict__ snid, int E) {
    int e = blockIdx.x * 256 + threadIdx.x;
    if (e < E) {
        int d = dst[e];
        int pos = atomicAdd(&next_pos[d], 1);
        ssrc[pos] = src[e];
        stype[pos] = etype[e];
        float deg = (float)max(counts[d], 1);
        snid[pos] = enorm[e] / deg;   // fold mean into per-edge coef
    }
}

__global__ __launch_bounds__(256) void gather_kernel(const int* __restrict__ entity,
                                                     const float* __restrict__ emb,
                                                     float* __restrict__ x, int total) {
    int i = blockIdx.x * 256 + threadIdx.x;
    if (i < total) {
        int n = i / DIMD;
        int d = i - n * DIMD;
        x[i] = emb[(size_t)entity[n] * DIMD + d];
    }
}

__global__ __launch_bounds__(256) void relu_kernel(float* __restrict__ p, int total4) {
    int i = blockIdx.x * 256 + threadIdx.x;
    if (i < total4) {
        float4 v = ((float4*)p)[i];
        v.x = fmaxf(v.x, 0.f); v.y = fmaxf(v.y, 0.f);
        v.z = fmaxf(v.z, 0.f); v.w = fmaxf(v.w, 0.f);
        ((float4*)p)[i] = v;
    }
}

// ---------------- Phase A: scatter into S (one wave per node) ----------------

__global__ __launch_bounds__(256) void phaseA_kernel(
        const float* __restrict__ x, const int* __restrict__ row_ptr,
        const int* __restrict__ ssrc, const int* __restrict__ stype,
        const float* __restrict__ snid, const float* __restrict__ att,
        float* __restrict__ S, int N) {
    __shared__ float att_s[1000];   // [R=100][B=10]
    for (int i = threadIdx.x; i < 1000; i += 256) att_s[i] = att[i];
    __syncthreads();

    int wave = threadIdx.x >> 6;
    int l = threadIdx.x & 63;
    int n = blockIdx.x * 4 + wave;
    if (n >= N) return;

    int e0 = row_ptr[n], e1 = row_ptr[n + 1];
    float acc0[NBASES];
    float acc1[NBASES];
#pragma unroll
    for (int b = 0; b < NBASES; ++b) { acc0[b] = 0.f; acc1[b] = 0.f; }
    bool hi = (l < DIMD - 64);   // lanes 0..35 also own d = 64+l

    // software-pipelined edge loop: prefetch next edge's meta + x row
    int t_cur = 0; float nv_cur = 0.f, xa = 0.f, xb = 0.f;
    if (e0 < e1) {
        int s0 = ssrc[e0];
        t_cur = stype[e0];
        nv_cur = snid[e0];
        const float* xr = x + (size_t)s0 * DIMD;
        xa = xr[l];
        xb = hi ? xr[64 + l] : 0.f;
    }
    for (int e = e0; e < e1; ++e) {
        int t_nxt = 0; float nv_nxt = 0.f, xa_n = 0.f, xb_n = 0.f;
        if (e + 1 < e1) {
            int sn = ssrc[e + 1];
            t_nxt = stype[e + 1];
            nv_nxt = snid[e + 1];
            const float* xr = x + (size_t)sn * DIMD;
            xa_n = xr[l];
            xb_n = hi ? xr[64 + l] : 0.f;
        }
        const float* ar = att_s + t_cur * NBASES;
#pragma unroll
        for (int b = 0; b < NBASES; ++b) {
            float c = ar[b] * nv_cur;
            acc0[b] += c * xa;
            acc1[b] += c * xb;
        }
        t_cur = t_nxt; nv_cur = nv_nxt; xa = xa_n; xb = xb_n;
    }
    float* Sr = S + (size_t)n * (NBASES * DIMD);
#pragma unroll
    for (int b = 0; b < NBASES; ++b) {
        Sr[b * DIMD + l] = acc0[b];
        if (hi) Sr[b * DIMD + 64 + l] = acc1[b];
    }
}

// ---------------- Phase B: out += A_tile @ B_tile (K-split, atomic accum) ----
// Tile 128 rows x 128 cols (100 valid), KC=32, 256 threads, 8x8 microtile.
// grid = 2 * ceil(N/128); bx&1 = K-split half. bias added by split 0.

__global__ __launch_bounds__(256) void phaseB_kernel(
        const float* __restrict__ S, const float* __restrict__ x,
        const float* __restrict__ Bm,   // [1000][100] basis flat
        const float* __restrict__ root, // [100][100]
        const float* __restrict__ bias, float* __restrict__ out, int N) {
    __shared__ __align__(16) float At[KC * 132];   // [kk][row^ (k4<<3)], stride 132
    __shared__ __align__(16) float Bt[KC * 144];   // [kk][col swizzled +4/32], stride 144

    int tid = threadIdx.x;
    int tx = tid & 15, ty = tid >> 4;
    int bx = blockIdx.x;
    int tile = bx >> 1, split = bx & 1;
    int n0 = tile * 128;
    int c0 = split ? SPLIT0 : 0;
    int c1 = split ? NCHUNK : SPLIT0;

    float acc[8][8];
#pragma unroll
    for (int j = 0; j < 8; ++j)
#pragma unroll
        for (int i = 0; i < 8; ++i) acc[j][i] = 0.f;

    for (int c = c0; c < c1; ++c) {
        int k0 = c * KC;
        __syncthreads();   // protect LDS from previous iteration's readers
        // stage A-tile transposed+swizzled: 128 rows x 32 k (1024 float4)
#pragma unroll
        for (int i = 0; i < 4; ++i) {
            int f4 = tid + i * 256;
            int r = f4 >> 3, k4 = f4 & 7;       // k4: float4 index within row
            int gr = min(n0 + r, N - 1);
            int kgb = k0 + k4 * 4;
            float4 v = make_float4(0.f, 0.f, 0.f, 0.f);
            if (kgb < 1000)      v = *(const float4*)(S + (size_t)gr * 1000 + kgb);
            else if (kgb < KTOT) v = *(const float4*)(x + (size_t)gr * DIMD + (kgb - 1000));
            int rsw = r ^ (k4 << 3);            // XOR-swizzle rows (bits 3..5)
            At[(k4 * 4 + 0) * 132 + rsw] = v.x;
            At[(k4 * 4 + 1) * 132 + rsw] = v.y;
            At[(k4 * 4 + 2) * 132 + rsw] = v.z;
            At[(k4 * 4 + 3) * 132 + rsw] = v.w;
        }
        // stage B-tile: 32 k x 128 cols (100 valid, rest zero)  (1024 float4)
#pragma unroll
        for (int i = 0; i < 4; ++i) {
            int f4 = tid + i * 256;
            int k = f4 >> 5, c4 = f4 & 31;
            int kg = k0 + k;
            float4 v = make_float4(0.f, 0.f, 0.f, 0.f);
            if (c4 < 25 && kg < KTOT) {
                v = (kg < 1000) ? *(const float4*)(Bm + (size_t)kg * DIMD + c4 * 4)
                                : *(const float4*)(root + (size_t)(kg - 1000) * DIMD + c4 * 4);
            }
            int phys = c4 * 4 + (c4 >> 3) * 4;   // +4 dwords per 32 floats
            *(float4*)&Bt[k * 144 + phys] = v;
        }
        __syncthreads();
#pragma unroll
        for (int k = 0; k < KC; ++k) {
            int q = (k >> 2) & 7;
            const float4* ap = (const float4*)&At[k * 132 + ((ty ^ q) << 3)];
            float4 a0 = ap[0], a1 = ap[1];
            const float4* bp = (const float4*)&Bt[k * 144 + tx * 8 + (tx >> 2) * 4];
            float4 b0 = bp[0], b1 = bp[1];
            float av[8] = {a0.x, a0.y, a0.z, a0.w, a1.x, a1.y, a1.z, a1.w};
            float bv[8] = {b0.x, b0.y, b0.z, b0.w, b1.x, b1.y, b1.z, b1.w};
#pragma unroll
            for (int j = 0; j < 8; ++j)
#pragma unroll
                for (int i = 0; i < 8; ++i) acc[j][i] += av[j] * bv[i];
        }
    }

    // epilogue: atomic accumulate (out pre-zeroed); bias added by split 0 only
#pragma unroll
    for (int j = 0; j < 8; ++j) {
        int r = n0 + ty * 8 + j;
        if (r < N) {
#pragma unroll
            for (int i = 0; i < 8; ++i) {
                int c = tx * 8 + i;
                if (c < DIMD) {
                    float v = acc[j][i];
                    if (split == 0) v += bias[c];
                    atomicAdd(&out[(size_t)r * DIMD + c], v);
                }
            }
        }
    }
}

// ---------------- driver ----------------

extern "C" void kernel_launch(void* const* d_in, const int* in_sizes, int n_in,
                              void* d_out, int out_size, void* d_ws, size_t ws_size,
                              hipStream_t stream) {
    const int* entity = (const int*)d_in[0];
    const int* edge_index = (const int*)d_in[1];
    const int* edge_type = (const int*)d_in[2];
    const float* edge_norm = (const float*)d_in[3];
    const float* emb = (const float*)d_in[4];
    const float* basisP[3] = {(const float*)d_in[5], (const float*)d_in[9], (const float*)d_in[13]};
    const float* attP[3]   = {(const float*)d_in[6], (const float*)d_in[10], (const float*)d_in[14]};
    const float* rootP[3]  = {(const float*)d_in[7], (const float*)d_in[11], (const float*)d_in[15]};
    const float* biasP[3]  = {(const float*)d_in[8], (const float*)d_in[12], (const float*)d_in[16]};

    const int N = in_sizes[0];
    const int E = in_sizes[1] / 2;
    const int* src = edge_index;
    const int* dst = edge_index + E;

    // workspace layout
    char* w = (char*)d_ws;
    float* S = (float*)w;            w += align256((size_t)N * NBASES * DIMD * 4);
    float* xA = (float*)w;           w += align256((size_t)N * DIMD * 4);
    float* xB = (float*)w;           w += align256((size_t)N * DIMD * 4);
    int* counts = (int*)w;           w += align256((size_t)N * 4);
    int* row_ptr = (int*)w;          w += align256((size_t)(N + 1) * 4);
    int* next_pos = (int*)w;         w += align256((size_t)N * 4);
    int* ssrc = (int*)w;             w += align256((size_t)E * 4);
    int* stype = (int*)w;            w += align256((size_t)E * 4);
    float* snid = (float*)w;         w += align256((size_t)E * 4);

    // ---- build CSR by dst (shared by all 5 convs) ----
    hipMemsetAsync(counts, 0, (size_t)N * 4, stream);
    int gE = (E + 255) / 256;
    hist_kernel<<<gE, 256, 0, stream>>>(dst, counts, E);
    scan_kernel<<<1, 1024, 0, stream>>>(counts, row_ptr, next_pos, N);
    scatter_kernel<<<gE, 256, 0, stream>>>(src, dst, edge_type, edge_norm, counts,
                                           next_pos, ssrc, stype, snid, E);
    // ---- x0 = emb[entity] ----
    int totalX = N * DIMD;
    gather_kernel<<<(totalX + 255) / 256, 256, 0, stream>>>(entity, emb, xA, totalX);

    // ---- 5 conv layers ----
    const int pidx[5] = {0, 0, 1, 0, 2};
    const int relu[5] = {0, 1, 0, 1, 0};
    float* bufin[5]  = {xA, xB, xA, xB, xA};
    float* bufout[5] = {xB, xA, xB, xA, (float*)d_out};

    int gA = (N + 3) / 4;
    int gB = ((N + 127) / 128) * 2;       // x2: K-split halves
    size_t outBytes = (size_t)N * DIMD * 4;
    int total4 = N * DIMD / 4;
    for (int l = 0; l < 5; ++l) {
        int p = pidx[l];
        hipMemsetAsync(bufout[l], 0, outBytes, stream);   // atomic accum target
        phaseA_kernel<<<gA, 256, 0, stream>>>(bufin[l], row_ptr, ssrc, stype, snid,
                                              attP[p], S, N);
        phaseB_kernel<<<gB, 256, 0, stream>>>(S, bufin[l], basisP[p], rootP[p], biasP[p],
                                              bufout[l], N);
        if (relu[l])
            relu_kernel<<<(total4 + 255) / 256, 256, 0, stream>>>(bufout[l], total4);
    }
}

// Round 4
// 2169.125 us; speedup vs baseline: 1.5794x; 1.5794x over previous
//
#include <hip/hip_runtime.h>

// RGCN on MI355X. CSR-by-dst built once, then per conv:
//   Phase A: S[n, b*100+d] = sum_{e: dst=n} att[type_e,b]*norm_e*invdeg_n * x[src_e,d]
//   Phase B: out = [S | x] @ [basis_flat ; root] + bias  (virtual K=1100 fp32 GEMM)
// R3: no atomics/K-split (R2 regression: 312MB HBM write amplification).
// Occupancy fix: 64-row tiles -> 782 blocks, ~3 blocks/CU resident.
// (R4 = identical resubmit of R3; R3 bench never ran: GPU acquisition timeout.)

#define DIMD 100
#define NBASES 10
#define KTOT 1100          // 1000 (S@basis) + 100 (x@root)
#define KC 32              // k per chunk
#define NCHUNK 35          // 35*32 = 1120 >= 1100 (tail zero-padded)

static inline size_t align256(size_t x) { return (x + 255) & ~(size_t)255; }

// ---------------- preprocessing kernels ----------------

__global__ __launch_bounds__(256) void hist_kernel(const int* __restrict__ dst,
                                                   int* __restrict__ counts, int E) {
    int e = blockIdx.x * 256 + threadIdx.x;
    if (e < E) atomicAdd(&counts[dst[e]], 1);
}

__global__ __launch_bounds__(1024) void scan_kernel(const int* __restrict__ counts,
                                                    int* __restrict__ row_ptr,
                                                    int* __restrict__ next_pos, int n) {
    __shared__ int part[1024];
    __shared__ int base_s[1024];
    int t = threadIdx.x;
    int chunk = (n + 1023) / 1024;
    int lo = t * chunk, hi = min(lo + chunk, n);
    int s = 0;
    for (int i = lo; i < hi; ++i) s += counts[i];
    part[t] = s;
    __syncthreads();
    if (t == 0) {
        int run = 0;
        for (int i = 0; i < 1024; ++i) { int v = part[i]; base_s[i] = run; run += v; }
        row_ptr[n] = run;   // == E
    }
    __syncthreads();
    int run = base_s[t];
    for (int i = lo; i < hi; ++i) {
        row_ptr[i] = run;
        next_pos[i] = run;
        run += counts[i];
    }
}

__global__ __launch_bounds__(256) void scatter_kernel(
        const int* __restrict__ src, const int* __restrict__ dst,
        const int* __restrict__ etype, const float* __restrict__ enorm,
        const int* __restrict__ counts, int* __restrict__ next_pos,
        int* __restrict__ ssrc, int* __restrict__ stype, float* __restrict__ snid, int E) {
    int e = blockIdx.x * 256 + threadIdx.x;
    if (e < E) {
        int d = dst[e];
        int pos = atomicAdd(&next_pos[d], 1);
        ssrc[pos] = src[e];
        stype[pos] = etype[e];
        float deg = (float)max(counts[d], 1);
        snid[pos] = enorm[e] / deg;   // fold mean into per-edge coef
    }
}

__global__ __launch_bounds__(256) void gather_kernel(const int* __restrict__ entity,
                                                     const float* __restrict__ emb,
                                                     float* __restrict__ x, int total) {
    int i = blockIdx.x * 256 + threadIdx.x;
    if (i < total) {
        int n = i / DIMD;
        int d = i - n * DIMD;
        x[i] = emb[(size_t)entity[n] * DIMD + d];
    }
}

// ---------------- Phase A: scatter into S (one wave per node) ----------------

__global__ __launch_bounds__(256) void phaseA_kernel(
        const float* __restrict__ x, const int* __restrict__ row_ptr,
        const int* __restrict__ ssrc, const int* __restrict__ stype,
        const float* __restrict__ snid, const float* __restrict__ att,
        float* __restrict__ S, int N) {
    __shared__ float att_s[1000];   // [R=100][B=10]
    for (int i = threadIdx.x; i < 1000; i += 256) att_s[i] = att[i];
    __syncthreads();

    int wave = threadIdx.x >> 6;
    int l = threadIdx.x & 63;
    int n = blockIdx.x * 4 + wave;
    if (n >= N) return;

    int e0 = row_ptr[n], e1 = row_ptr[n + 1];
    float acc0[NBASES];
    float acc1[NBASES];
#pragma unroll
    for (int b = 0; b < NBASES; ++b) { acc0[b] = 0.f; acc1[b] = 0.f; }
    bool hi = (l < DIMD - 64);   // lanes 0..35 also own d = 64+l

    // software-pipelined edge loop: prefetch next edge's meta + x row
    int t_cur = 0; float nv_cur = 0.f, xa = 0.f, xb = 0.f;
    if (e0 < e1) {
        int s0 = ssrc[e0];
        t_cur = stype[e0];
        nv_cur = snid[e0];
        const float* xr = x + (size_t)s0 * DIMD;
        xa = xr[l];
        xb = hi ? xr[64 + l] : 0.f;
    }
    for (int e = e0; e < e1; ++e) {
        int t_nxt = 0; float nv_nxt = 0.f, xa_n = 0.f, xb_n = 0.f;
        if (e + 1 < e1) {
            int sn = ssrc[e + 1];
            t_nxt = stype[e + 1];
            nv_nxt = snid[e + 1];
            const float* xr = x + (size_t)sn * DIMD;
            xa_n = xr[l];
            xb_n = hi ? xr[64 + l] : 0.f;
        }
        const float* ar = att_s + t_cur * NBASES;
#pragma unroll
        for (int b = 0; b < NBASES; ++b) {
            float c = ar[b] * nv_cur;
            acc0[b] += c * xa;
            acc1[b] += c * xb;
        }
        t_cur = t_nxt; nv_cur = nv_nxt; xa = xa_n; xb = xb_n;
    }
    float* Sr = S + (size_t)n * (NBASES * DIMD);
#pragma unroll
    for (int b = 0; b < NBASES; ++b) {
        Sr[b * DIMD + l] = acc0[b];
        if (hi) Sr[b * DIMD + 64 + l] = acc1[b];
    }
}

// ---------------- Phase B: out = [S|x] @ [Bm;root] + bias ----------------
// Tile 64 rows x 128 cols (100 valid), KC=32, 256 threads, 4x8 microtile.
// grid = ceil(N/64) = 782 blocks -> ~3 resident blocks/CU (occupancy fix).

__global__ __launch_bounds__(256) void phaseB_kernel(
        const float* __restrict__ S, const float* __restrict__ x,
        const float* __restrict__ Bm,   // [1000][100] basis flat
        const float* __restrict__ root, // [100][100]
        const float* __restrict__ bias, float* __restrict__ out,
        int N, int do_relu) {
    __shared__ __align__(16) float At[KC * 68];    // [k][row ^ ((k>>2)<<3)], stride 68
    __shared__ __align__(16) float Bt[KC * 144];   // [k][col swizzled +4/32], stride 144

    int tid = threadIdx.x;
    int tx = tid & 15, ty = tid >> 4;
    int n0 = blockIdx.x * 64;

    float acc[4][8];
#pragma unroll
    for (int j = 0; j < 4; ++j)
#pragma unroll
        for (int i = 0; i < 8; ++i) acc[j][i] = 0.f;

    for (int c = 0; c < NCHUNK; ++c) {
        int k0 = c * KC;
        __syncthreads();   // protect LDS from previous iteration's readers
        // stage A-tile transposed+swizzled: 64 rows x 32 k (512 float4, 2/thread)
#pragma unroll
        for (int i = 0; i < 2; ++i) {
            int f4 = tid + i * 256;
            int r = f4 >> 3, k4 = f4 & 7;       // k4: float4 index within row
            int gr = min(n0 + r, N - 1);
            int kgb = k0 + k4 * 4;
            float4 v = make_float4(0.f, 0.f, 0.f, 0.f);
            if (kgb < 1000)      v = *(const float4*)(S + (size_t)gr * 1000 + kgb);
            else if (kgb < KTOT) v = *(const float4*)(x + (size_t)gr * DIMD + (kgb - 1000));
            int rsw = r ^ (k4 << 3);            // XOR-swizzle (2-way max on write = free)
            At[(k4 * 4 + 0) * 68 + rsw] = v.x;
            At[(k4 * 4 + 1) * 68 + rsw] = v.y;
            At[(k4 * 4 + 2) * 68 + rsw] = v.z;
            At[(k4 * 4 + 3) * 68 + rsw] = v.w;
        }
        // stage B-tile: 32 k x 128 cols (100 valid, rest zero)  (1024 float4, 4/thread)
#pragma unroll
        for (int i = 0; i < 4; ++i) {
            int f4 = tid + i * 256;
            int k = f4 >> 5, c4 = f4 & 31;
            int kg = k0 + k;
            float4 v = make_float4(0.f, 0.f, 0.f, 0.f);
            if (c4 < 25 && kg < KTOT) {
                v = (kg < 1000) ? *(const float4*)(Bm + (size_t)kg * DIMD + c4 * 4)
                                : *(const float4*)(root + (size_t)(kg - 1000) * DIMD + c4 * 4);
            }
            int phys = c4 * 4 + (c4 >> 3) * 4;   // +4 dwords per 32 floats
            *(float4*)&Bt[k * 144 + phys] = v;
        }
        __syncthreads();
#pragma unroll
        for (int k = 0; k < KC; ++k) {
            int q = k >> 2;                      // matches write-side swizzle
            float4 a0 = *(const float4*)&At[k * 68 + ((ty * 4) ^ (q << 3))];
            const float4* bp = (const float4*)&Bt[k * 144 + tx * 8 + (tx >> 2) * 4];
            float4 b0 = bp[0], b1 = bp[1];
            float av[4] = {a0.x, a0.y, a0.z, a0.w};
            float bv[8] = {b0.x, b0.y, b0.z, b0.w, b1.x, b1.y, b1.z, b1.w};
#pragma unroll
            for (int j = 0; j < 4; ++j)
#pragma unroll
                for (int i = 0; i < 8; ++i) acc[j][i] += av[j] * bv[i];
        }
    }

    // epilogue: + bias, optional relu, direct store of valid 100 cols
#pragma unroll
    for (int j = 0; j < 4; ++j) {
        int r = n0 + ty * 4 + j;
        if (r < N) {
#pragma unroll
            for (int i = 0; i < 8; ++i) {
                int c = tx * 8 + i;
                if (c < DIMD) {
                    float v = acc[j][i] + bias[c];
                    if (do_relu) v = fmaxf(v, 0.f);
                    out[(size_t)r * DIMD + c] = v;
                }
            }
        }
    }
}

// ---------------- driver ----------------

extern "C" void kernel_launch(void* const* d_in, const int* in_sizes, int n_in,
                              void* d_out, int out_size, void* d_ws, size_t ws_size,
                              hipStream_t stream) {
    const int* entity = (const int*)d_in[0];
    const int* edge_index = (const int*)d_in[1];
    const int* edge_type = (const int*)d_in[2];
    const float* edge_norm = (const float*)d_in[3];
    const float* emb = (const float*)d_in[4];
    const float* basisP[3] = {(const float*)d_in[5], (const float*)d_in[9], (const float*)d_in[13]};
    const float* attP[3]   = {(const float*)d_in[6], (const float*)d_in[10], (const float*)d_in[14]};
    const float* rootP[3]  = {(const float*)d_in[7], (const float*)d_in[11], (const float*)d_in[15]};
    const float* biasP[3]  = {(const float*)d_in[8], (const float*)d_in[12], (const float*)d_in[16]};

    const int N = in_sizes[0];
    const int E = in_sizes[1] / 2;
    const int* src = edge_index;
    const int* dst = edge_index + E;

    // workspace layout
    char* w = (char*)d_ws;
    float* S = (float*)w;            w += align256((size_t)N * NBASES * DIMD * 4);
    float* xA = (float*)w;           w += align256((size_t)N * DIMD * 4);
    float* xB = (float*)w;           w += align256((size_t)N * DIMD * 4);
    int* counts = (int*)w;           w += align256((size_t)N * 4);
    int* row_ptr = (int*)w;          w += align256((size_t)(N + 1) * 4);
    int* next_pos = (int*)w;         w += align256((size_t)N * 4);
    int* ssrc = (int*)w;             w += align256((size_t)E * 4);
    int* stype = (int*)w;            w += align256((size_t)E * 4);
    float* snid = (float*)w;         w += align256((size_t)E * 4);

    // ---- build CSR by dst (shared by all 5 convs) ----
    hipMemsetAsync(counts, 0, (size_t)N * 4, stream);
    int gE = (E + 255) / 256;
    hist_kernel<<<gE, 256, 0, stream>>>(dst, counts, E);
    scan_kernel<<<1, 1024, 0, stream>>>(counts, row_ptr, next_pos, N);
    scatter_kernel<<<gE, 256, 0, stream>>>(src, dst, edge_type, edge_norm, counts,
                                           next_pos, ssrc, stype, snid, E);
    // ---- x0 = emb[entity] ----
    int totalX = N * DIMD;
    gather_kernel<<<(totalX + 255) / 256, 256, 0, stream>>>(entity, emb, xA, totalX);

    // ---- 5 conv layers ----
    const int pidx[5] = {0, 0, 1, 0, 2};
    const int relu[5] = {0, 1, 0, 1, 0};
    float* bufin[5]  = {xA, xB, xA, xB, xA};
    float* bufout[5] = {xB, xA, xB, xA, (float*)d_out};

    int gA = (N + 3) / 4;
    int gB = (N + 63) / 64;
    for (int l = 0; l < 5; ++l) {
        int p = pidx[l];
        phaseA_kernel<<<gA, 256, 0, stream>>>(bufin[l], row_ptr, ssrc, stype, snid,
                                              attP[p], S, N);
        phaseB_kernel<<<gB, 256, 0, stream>>>(S, bufin[l], basisP[p], rootP[p], biasP[p],
                                              bufout[l], N, relu[l]);
    }
}